// Round 1
// baseline (2974.460 us; speedup 1.0000x reference)
//
#include <hip/hip_runtime.h>

#define N_NODES 100000
#define N_EDGES 3200000
#define D 128

// ---------------------------------------------------------------------------
// Kernel 0: out[n, f] = bias[f]   (harness poisons d_out before every launch)
// ---------------------------------------------------------------------------
__global__ __launch_bounds__(256) void init_out(const float* __restrict__ bias,
                                                float* __restrict__ out) {
    int i = blockIdx.x * 256 + threadIdx.x;
    if (i < N_NODES * D) out[i] = bias[i & (D - 1)];
}

// ---------------------------------------------------------------------------
// Kernel 1: S = X @ W   (S in workspace)
// W (128x128 fp32 = 64 KB) staged in LDS once per block.
// One wave per node row: lane computes outputs f=lane and f=lane+64.
// LDS banks: w_lds[k*128 + lane] -> bank = lane%32, 2-way aliasing (free).
// x broadcast read (same address across wave) is conflict-free.
// ---------------------------------------------------------------------------
__global__ __launch_bounds__(256) void gemm_xw(const float* __restrict__ X,
                                               const float* __restrict__ W,
                                               float* __restrict__ S) {
    __shared__ float w_lds[D * D];      // 64 KB
    __shared__ float x_lds[4][D];       // one row per wave

    for (int i = threadIdx.x; i < (D * D) / 4; i += 256) {
        ((float4*)w_lds)[i] = ((const float4*)W)[i];
    }
    __syncthreads();

    const int wave = threadIdx.x >> 6;
    const int lane = threadIdx.x & 63;

    for (int node = blockIdx.x * 4 + wave; node < N_NODES;
         node += gridDim.x * 4) {
        // Stage this node's x row into LDS (within-wave: no barrier needed,
        // compiler inserts lgkmcnt wait before dependent reads).
        float2 xv = ((const float2*)(X + (size_t)node * D))[lane];
        x_lds[wave][2 * lane]     = xv.x;
        x_lds[wave][2 * lane + 1] = xv.y;

        float acc0 = 0.f, acc1 = 0.f;
#pragma unroll 8
        for (int k = 0; k < D; ++k) {
            float xk = x_lds[wave][k];                 // broadcast
            acc0 += xk * w_lds[k * D + lane];          // 2-way bank (free)
            acc1 += xk * w_lds[k * D + 64 + lane];
        }
        S[(size_t)node * D + lane]      = acc0;
        S[(size_t)node * D + 64 + lane] = acc1;
    }
}

// ---------------------------------------------------------------------------
// Kernel 2: out[dst] += val * S[src]   (one wave per edge)
// Lane handles features 2*lane, 2*lane+1: coalesced float2 gather from S,
// two coalesced fp32 atomics into out.
// ---------------------------------------------------------------------------
__global__ __launch_bounds__(256) void scatter_edges(
        const float* __restrict__ S,
        const int* __restrict__ esrc,
        const int* __restrict__ edst,
        const float* __restrict__ eval,
        float* __restrict__ out) {
    const int lane   = threadIdx.x & 63;
    const int waveId = (blockIdx.x * 256 + threadIdx.x) >> 6;
    const int nWaves = (gridDim.x * 256) >> 6;

    for (int e = waveId; e < N_EDGES; e += nWaves) {
        const int   s = esrc[e];   // uniform across wave (broadcast load)
        const int   d = edst[e];
        const float v = eval[e];

        const float2 sv = ((const float2*)(S + (size_t)s * D))[lane];
        float* op = out + (size_t)d * D + 2 * lane;
        atomicAdd(op + 0, v * sv.x);
        atomicAdd(op + 1, v * sv.y);
    }
}

extern "C" void kernel_launch(void* const* d_in, const int* in_sizes, int n_in,
                              void* d_out, int out_size, void* d_ws, size_t ws_size,
                              hipStream_t stream) {
    const float* X    = (const float*)d_in[0];   // [N_NODES, D]
    const int*   esrc = (const int*)  d_in[1];   // [N_EDGES]
    const int*   edst = (const int*)  d_in[2];   // [N_EDGES]
    const float* eval = (const float*)d_in[3];   // [N_EDGES]
    const float* W    = (const float*)d_in[4];   // [D, D]
    const float* bias = (const float*)d_in[5];   // [D]
    float* out = (float*)d_out;
    float* S   = (float*)d_ws;                   // [N_NODES, D] = 51.2 MB

    // Init output with bias (independent of GEMM; same stream serializes
    // before scatter, which is the only consumer).
    init_out<<<(N_NODES * D + 255) / 256, 256, 0, stream>>>(bias, out);

    // S = X @ W
    gemm_xw<<<(N_NODES + 3) / 4, 256, 0, stream>>>(X, W, S);

    // out[dst] += val * S[src]
    const int edgeBlocks = (N_EDGES + 3) / 4;    // 4 waves (edges) per block
    scatter_edges<<<edgeBlocks, 256, 0, stream>>>(S, esrc, edst, eval, out);
}

// Round 2
// 853.885 us; speedup vs baseline: 3.4834x; 3.4834x over previous
//
#include <hip/hip_runtime.h>

#define N_NODES 100000
#define N_EDGES 3200000
#define D 128

// ---------------------------------------------------------------------------
// Workspace layout (bytes)
// ---------------------------------------------------------------------------
static const size_t OFF_S      = 0;          // N*D floats      = 51,200,000
static const size_t OFF_SORTED = 51200000;   // E int2          = 25,600,000
static const size_t OFF_COUNTS = 76800000;   // N ints          =    400,000
static const size_t OFF_OFFS   = 77200000;   // N ints
static const size_t OFF_CURSOR = 77600000;   // N ints
static const size_t OFF_BSUM   = 78000000;   // 512 B
static const size_t WS_NEEDED  = 78000512;

#define SCAN_B 1024                          // elements per scan block
#define NSB    98                            // ceil(N_NODES / SCAN_B)

// ---------------------------------------------------------------------------
// S = X @ W.  W (64 KB) staged in LDS once per block; grid-stride over nodes
// so W staging is amortized (~2048 blocks -> 128 MB total W fetch vs 1.6 GB).
// ---------------------------------------------------------------------------
__global__ __launch_bounds__(256) void gemm_xw(const float* __restrict__ X,
                                               const float* __restrict__ W,
                                               float* __restrict__ S) {
    __shared__ float w_lds[D * D];      // 64 KB
    __shared__ float x_lds[4][D];

    for (int i = threadIdx.x; i < (D * D) / 4; i += 256)
        ((float4*)w_lds)[i] = ((const float4*)W)[i];
    __syncthreads();

    const int wave = threadIdx.x >> 6;
    const int lane = threadIdx.x & 63;

    for (int node = blockIdx.x * 4 + wave; node < N_NODES;
         node += gridDim.x * 4) {
        float2 xv = ((const float2*)(X + (size_t)node * D))[lane];
        x_lds[wave][2 * lane]     = xv.x;
        x_lds[wave][2 * lane + 1] = xv.y;

        float acc0 = 0.f, acc1 = 0.f;
#pragma unroll 8
        for (int k = 0; k < D; ++k) {
            float xk = x_lds[wave][k];
            acc0 += xk * w_lds[k * D + lane];
            acc1 += xk * w_lds[k * D + 64 + lane];
        }
        S[(size_t)node * D + lane]      = acc0;
        S[(size_t)node * D + 64 + lane] = acc1;
    }
}

// ---------------------------------------------------------------------------
// Counting sort by dst: histogram -> 3-pass exclusive scan -> record scatter
// ---------------------------------------------------------------------------
__global__ __launch_bounds__(256) void hist_dst(const int* __restrict__ edst,
                                                int* __restrict__ counts) {
    int e = blockIdx.x * 256 + threadIdx.x;
    if (e < N_EDGES) atomicAdd(&counts[edst[e]], 1);
}

__global__ __launch_bounds__(256) void scan_p1(const int* __restrict__ counts,
                                               int* __restrict__ bsum) {
    __shared__ int sc[256];
    const int t = threadIdx.x;
    const int base = blockIdx.x * SCAN_B + t * 4;
    int s = 0;
#pragma unroll
    for (int j = 0; j < 4; ++j) {
        int i = base + j;
        if (i < N_NODES) s += counts[i];
    }
    sc[t] = s;
    __syncthreads();
    for (int off = 128; off > 0; off >>= 1) {
        if (t < off) sc[t] += sc[t + off];
        __syncthreads();
    }
    if (t == 0) bsum[blockIdx.x] = sc[0];
}

__global__ __launch_bounds__(128) void scan_p2(int* __restrict__ bsum) {
    __shared__ int sc[128];
    const int t = threadIdx.x;
    int v = (t < NSB) ? bsum[t] : 0;
    sc[t] = v;
    __syncthreads();
    for (int off = 1; off < 128; off <<= 1) {
        int u = (t >= off) ? sc[t - off] : 0;
        __syncthreads();
        if (t >= off) sc[t] += u;
        __syncthreads();
    }
    if (t < NSB) bsum[t] = (t == 0) ? 0 : sc[t - 1];   // exclusive
}

__global__ __launch_bounds__(256) void scan_p3(const int* __restrict__ counts,
                                               const int* __restrict__ bsum,
                                               int* __restrict__ offs,
                                               int* __restrict__ cursor) {
    __shared__ int sc[256];
    const int t = threadIdx.x;
    const int base = blockIdx.x * SCAN_B + t * 4;
    int v[4];
    int s = 0;
#pragma unroll
    for (int j = 0; j < 4; ++j) {
        int i = base + j;
        v[j] = (i < N_NODES) ? counts[i] : 0;
        s += v[j];
    }
    sc[t] = s;
    __syncthreads();
    for (int off = 1; off < 256; off <<= 1) {
        int u = (t >= off) ? sc[t - off] : 0;
        __syncthreads();
        if (t >= off) sc[t] += u;
        __syncthreads();
    }
    int run = bsum[blockIdx.x] + ((t == 0) ? 0 : sc[t - 1]);
#pragma unroll
    for (int j = 0; j < 4; ++j) {
        int i = base + j;
        if (i < N_NODES) { offs[i] = run; cursor[i] = run; }
        run += v[j];
    }
}

__global__ __launch_bounds__(256) void scatter_sort(const int* __restrict__ esrc,
                                                    const int* __restrict__ edst,
                                                    const float* __restrict__ eval,
                                                    int* __restrict__ cursor,
                                                    int2* __restrict__ sorted) {
    int e = blockIdx.x * 256 + threadIdx.x;
    if (e >= N_EDGES) return;
    int d = edst[e];
    int p = atomicAdd(&cursor[d], 1);
    sorted[p] = make_int2(esrc[e], __float_as_int(eval[e]));
}

// ---------------------------------------------------------------------------
// One wave per dst node: coalesced 64-wide edge-record load, shfl broadcast,
// coalesced 512 B S-row gathers, register accumulate, single biased store.
// ---------------------------------------------------------------------------
__global__ __launch_bounds__(256) void reduce_segments(
        const float* __restrict__ S,
        const int2* __restrict__ sorted,
        const int* __restrict__ offs,
        const float* __restrict__ bias,
        float* __restrict__ out) {
    const int lane = threadIdx.x & 63;
    const int node = (blockIdx.x * 256 + threadIdx.x) >> 6;
    if (node >= N_NODES) return;

    const int beg = offs[node];
    const int end = (node == N_NODES - 1) ? N_EDGES : offs[node + 1];

    float acc0x = 0.f, acc0y = 0.f, acc1x = 0.f, acc1y = 0.f;

    for (int base = beg; base < end; base += 64) {
        const int m = min(64, end - base);
        int2 rec = make_int2(0, 0);
        if (base + lane < end) rec = sorted[base + lane];

        int j = 0;
        for (; j + 1 < m; j += 2) {             // 2-way ILP on the gathers
            int   s0 = __shfl(rec.x, j);
            float v0 = __int_as_float(__shfl(rec.y, j));
            int   s1 = __shfl(rec.x, j + 1);
            float v1 = __int_as_float(__shfl(rec.y, j + 1));
            float2 a = ((const float2*)(S + (size_t)s0 * D))[lane];
            float2 b = ((const float2*)(S + (size_t)s1 * D))[lane];
            acc0x += v0 * a.x; acc0y += v0 * a.y;
            acc1x += v1 * b.x; acc1y += v1 * b.y;
        }
        if (j < m) {
            int   s0 = __shfl(rec.x, j);
            float v0 = __int_as_float(__shfl(rec.y, j));
            float2 a = ((const float2*)(S + (size_t)s0 * D))[lane];
            acc0x += v0 * a.x; acc0y += v0 * a.y;
        }
    }

    float2 b = ((const float2*)bias)[lane];
    float2 r = make_float2(acc0x + acc1x + b.x, acc0y + acc1y + b.y);
    ((float2*)(out + (size_t)node * D))[lane] = r;
}

// ---------------------------------------------------------------------------
// Fallback path (ws too small): bias-init + per-edge atomics (round-1 kernel)
// ---------------------------------------------------------------------------
__global__ __launch_bounds__(256) void init_out(const float* __restrict__ bias,
                                                float* __restrict__ out) {
    int i = blockIdx.x * 256 + threadIdx.x;
    if (i < N_NODES * D) out[i] = bias[i & (D - 1)];
}

__global__ __launch_bounds__(256) void scatter_edges(
        const float* __restrict__ S,
        const int* __restrict__ esrc,
        const int* __restrict__ edst,
        const float* __restrict__ eval,
        float* __restrict__ out) {
    const int lane   = threadIdx.x & 63;
    const int waveId = (blockIdx.x * 256 + threadIdx.x) >> 6;
    const int nWaves = (gridDim.x * 256) >> 6;
    for (int e = waveId; e < N_EDGES; e += nWaves) {
        const int   s = esrc[e];
        const int   d = edst[e];
        const float v = eval[e];
        const float2 sv = ((const float2*)(S + (size_t)s * D))[lane];
        float* op = out + (size_t)d * D + 2 * lane;
        atomicAdd(op + 0, v * sv.x);
        atomicAdd(op + 1, v * sv.y);
    }
}

extern "C" void kernel_launch(void* const* d_in, const int* in_sizes, int n_in,
                              void* d_out, int out_size, void* d_ws, size_t ws_size,
                              hipStream_t stream) {
    const float* X    = (const float*)d_in[0];
    const int*   esrc = (const int*)  d_in[1];
    const int*   edst = (const int*)  d_in[2];
    const float* eval = (const float*)d_in[3];
    const float* W    = (const float*)d_in[4];
    const float* bias = (const float*)d_in[5];
    float* out = (float*)d_out;

    char* ws = (char*)d_ws;
    float* S      = (float*)(ws + OFF_S);
    int2*  sorted = (int2*) (ws + OFF_SORTED);
    int*   counts = (int*)  (ws + OFF_COUNTS);
    int*   offs   = (int*)  (ws + OFF_OFFS);
    int*   cursor = (int*)  (ws + OFF_CURSOR);
    int*   bsum   = (int*)  (ws + OFF_BSUM);

    const int edgeGrid = (N_EDGES + 255) / 256;   // 12500

    if (ws_size >= WS_NEEDED) {
        // S = X @ W
        gemm_xw<<<2048, 256, 0, stream>>>(X, W, S);

        // Counting sort of edges by dst
        hipMemsetAsync(counts, 0, (size_t)N_NODES * 4, stream);
        hist_dst<<<edgeGrid, 256, 0, stream>>>(edst, counts);
        scan_p1<<<NSB, 256, 0, stream>>>(counts, bsum);
        scan_p2<<<1, 128, 0, stream>>>(bsum);
        scan_p3<<<NSB, 256, 0, stream>>>(counts, bsum, offs, cursor);
        scatter_sort<<<edgeGrid, 256, 0, stream>>>(esrc, edst, eval, cursor, sorted);

        // Segmented reduction: out[n] = bias + sum val * S[src]
        reduce_segments<<<(N_NODES + 3) / 4, 256, 0, stream>>>(
            S, sorted, offs, bias, out);
    } else {
        // Fallback: atomic scatter (needs only S in ws)
        init_out<<<(N_NODES * D + 255) / 256, 256, 0, stream>>>(bias, out);
        gemm_xw<<<2048, 256, 0, stream>>>(X, W, S);
        scatter_edges<<<(N_EDGES + 3) / 4, 256, 0, stream>>>(S, esrc, edst, eval, out);
    }
}